// Round 13
// baseline (1456.866 us; speedup 1.0000x reference)
//
#include <hip/hip_runtime.h>
#include <math.h>

namespace {

constexpr int BTOT = 131072;
constexpr int NO = 24;
constexpr int NSTEPS = 23;

// XLA:GPU(ROCm): logistic = 1/(1+exp(-x)) with native ocml expf.
__device__ __forceinline__ float xsig(float x) {
#pragma clang fp contract(off)
  return 1.0f / (1.0f + expf(-x));
}

// XLA:GPU row-reduce, extent n<=11 (pow2-padded to 16, init 0) — exact clone
// of the round-11 passing version (redundant per lane).
__device__ __forceinline__ float vsumN(const float* x, int n) {
#pragma clang fp contract(off)
  float t[16];
#pragma unroll
  for (int l = 0; l < 16; ++l) t[l] = (l < n) ? x[l] : 0.f;
  float a[8], b[4], c[2];
#pragma unroll
  for (int l = 0; l < 8; ++l) a[l] = t[l] + t[l + 8];
#pragma unroll
  for (int l = 0; l < 4; ++l) b[l] = a[l] + a[l + 4];
#pragma unroll
  for (int l = 0; l < 2; ++l) c[l] = b[l] + b[l + 2];
  return c[0] + c[1];
}

// jax.lax.associative_scan(add) exact clone for n in [1,11].
__device__ __forceinline__ void ascan11(float* x, int n) {
#pragma clang fp contract(off)
  if (n < 2) return;
  const int m1 = n >> 1;
  float r1[5];
#pragma unroll
  for (int i = 0; i < 5; ++i)
    if (2 * i + 1 < n) r1[i] = x[2 * i] + x[2 * i + 1];
  float r2[2] = {0.f, 0.f};
#pragma unroll
  for (int i = 0; i < 2; ++i)
    if (2 * i + 1 < m1) r2[i] = r1[2 * i] + r1[2 * i + 1];
  const int m2 = m1 >> 1;
  float s2[2];
  s2[0] = r2[0];
  s2[1] = (m2 == 2) ? (r2[0] + r2[1]) : r2[1];
  float s1[5];
  s1[0] = r1[0];
  if (1 < m1) s1[1] = s2[0];
  if (2 < m1) s1[2] = s2[0] + r1[2];
  if (3 < m1) s1[3] = s2[1];
  if (4 < m1) s1[4] = s2[1] + r1[4];
  float o[11];
  o[0] = x[0];
#pragma unroll
  for (int i = 0; i < 5; ++i) {
    if (2 * i + 1 < n) o[2 * i + 1] = s1[i];
    if (2 * i + 2 < n) o[2 * i + 2] = s1[i] + x[2 * i + 2];
  }
#pragma unroll
  for (int i = 0; i < 11; ++i)
    if (i < n) x[i] = o[i];
}

// 8 lanes per element: lane lg owns rows/outputs j = lg, lg+8, lg+16.
// 256 threads/block = 32 elements/block; grid = 4096.
__global__ __launch_bounds__(256) void policy_kernel(
    const float* __restrict__ W_ih, const float* __restrict__ W_hh,
    const float* __restrict__ b_ih, const float* __restrict__ b_hh,
    const float* __restrict__ W_lin, const float* __restrict__ b_lin,
    const float* __restrict__ rand_u, float* __restrict__ out) {
#pragma clang fp contract(off)
  // --- LDS staging ---
  // s_wih[col][j*4+g] : W_ih column col, gate-interleaved per j (float4/j)
  __shared__ __align__(16) float s_wih[23 * 100];
  // s_whh[lg][ (s*4+g)*24 + k ], per-lane stride 292 (1168B: bank-spread, 16B-align)
  __shared__ __align__(16) float s_whh[8 * 292];
  // s_wlin[lg][ s*24 + k ], per-lane stride 76
  __shared__ __align__(16) float s_wlin[8 * 76];
  __shared__ float s_bih[96], s_bhh[96], s_blin[24];

  for (int t = threadIdx.x; t < 23 * 96; t += 256) {
    const int col = t / 96;
    const int r = t - col * 96;  // r = j*4+g
    s_wih[col * 100 + r] = W_ih[((r & 3) * 24 + (r >> 2)) * NO + col];
  }
  for (int t = threadIdx.x; t < 8 * 288; t += 256) {
    const int lg = t / 288;
    const int r = t - lg * 288;  // r = (s*4+g)*24 + k
    const int sg = r / 24, k = r - sg * 24;
    const int s = sg >> 2, g = sg & 3;
    s_whh[lg * 292 + r] = W_hh[(g * 24 + lg + 8 * s) * 24 + k];
  }
  for (int t = threadIdx.x; t < 8 * 72; t += 256) {
    const int lg = t / 72;
    const int r = t - lg * 72;  // r = s*24 + k
    const int s = r / 24, k = r - s * 24;
    s_wlin[lg * 76 + r] = W_lin[(lg + 8 * s) * 24 + k];
  }
  for (int t = threadIdx.x; t < 96; t += 256) {
    s_bih[t] = b_ih[t];
    s_bhh[t] = b_hh[t];
  }
  for (int t = threadIdx.x; t < 24; t += 256) s_blin[t] = b_lin[t];
  __syncthreads();

  const int glane = threadIdx.x & 7;
  const int eb = (blockIdx.x * 256 + threadIdx.x) >> 3;  // element id

  float* actions = out;                    // [B][24]
  float* probs = out + (size_t)BTOT * NO;  // [B][23]

  float h_all[24];
#pragma unroll
  for (int k = 0; k < 24; ++k) h_all[k] = 0.f;
  float c_s[3] = {0.f, 0.f, 0.f};

  int x_idx = -1;  // -1 => x all zeros (first step)
  int step = 0;
  if (glane == 0) actions[(size_t)eb * NO + 23] = 0.0f;

#pragma unroll 1
  for (int counter = 0; counter < 12; ++counter) {
#pragma unroll 1
    for (int sub = (counter == 0) ? 1 : 0; sub < 2; ++sub) {
      const int xcol = (x_idx < 0) ? 0 : x_idx;
      const bool hasx = (x_idx >= 0);

      // ===== LSTM cell: lane computes rows j=glane+8s, all 4 gates =====
      float hn[3];
#pragma unroll
      for (int s = 0; s < 3; ++s) {
        const int j = glane + 8 * s;
        const int base = glane * 292 + s * 96;  // (s*4+g)*24, g=0
        float4 wv = make_float4(0.f, 0.f, 0.f, 0.f);
        if (hasx)
          wv = *reinterpret_cast<const float4*>(&s_wih[xcol * 100 + j * 4]);
        float ai = 0.f, af = 0.f, ag = 0.f, ao = 0.f;
#pragma unroll
        for (int kk = 0; kk < 6; ++kk) {
          const float4 wi = *reinterpret_cast<const float4*>(&s_whh[base + kk * 4]);
          const float4 wf = *reinterpret_cast<const float4*>(&s_whh[base + 24 + kk * 4]);
          const float4 wg = *reinterpret_cast<const float4*>(&s_whh[base + 48 + kk * 4]);
          const float4 wo = *reinterpret_cast<const float4*>(&s_whh[base + 72 + kk * 4]);
          const float h0 = h_all[kk * 4 + 0], h1 = h_all[kk * 4 + 1];
          const float h2 = h_all[kk * 4 + 2], h3 = h_all[kk * 4 + 3];
          ai = fmaf(wi.x, h0, ai); ai = fmaf(wi.y, h1, ai);
          ai = fmaf(wi.z, h2, ai); ai = fmaf(wi.w, h3, ai);
          af = fmaf(wf.x, h0, af); af = fmaf(wf.y, h1, af);
          af = fmaf(wf.z, h2, af); af = fmaf(wf.w, h3, af);
          ag = fmaf(wg.x, h0, ag); ag = fmaf(wg.y, h1, ag);
          ag = fmaf(wg.z, h2, ag); ag = fmaf(wg.w, h3, ag);
          ao = fmaf(wo.x, h0, ao); ao = fmaf(wo.y, h1, ao);
          ao = fmaf(wo.z, h2, ao); ao = fmaf(wo.w, h3, ao);
        }
        const float gi = (((hasx ? wv.x : 0.f) + ai) + s_bih[j]) + s_bhh[j];
        const float gf = (((hasx ? wv.y : 0.f) + af) + s_bih[j + 24]) + s_bhh[j + 24];
        const float gg = (((hasx ? wv.z : 0.f) + ag) + s_bih[j + 48]) + s_bhh[j + 48];
        const float go = (((hasx ? wv.w : 0.f) + ao) + s_bih[j + 72]) + s_bhh[j + 72];
        const float t1 = xsig(gf) * c_s[s];
        const float t2 = xsig(gi) * tanhf(gg);
        const float c2 = t1 + t2;
        c_s[s] = c2;
        hn[s] = xsig(go) * tanhf(c2);
      }
      // broadcast h: h_all[k] from lane (k&7), slot (k>>3)
#pragma unroll
      for (int k = 0; k < 24; ++k) {
        const int slot = k >> 3;
        const float v = (slot == 0) ? hn[0] : (slot == 1) ? hn[1] : hn[2];
        h_all[k] = __shfl(v, k & 7, 8);
      }

      // ===== p = softmax(h @ W_lin.T + b_lin): lane owns o=glane+8s =====
      float po[3];
#pragma unroll
      for (int s = 0; s < 3; ++s) {
        const int base2 = glane * 76 + s * 24;
        float a = 0.f;
#pragma unroll
        for (int kk = 0; kk < 6; ++kk) {
          const float4 w = *reinterpret_cast<const float4*>(&s_wlin[base2 + kk * 4]);
          a = fmaf(w.x, h_all[kk * 4 + 0], a);
          a = fmaf(w.y, h_all[kk * 4 + 1], a);
          a = fmaf(w.z, h_all[kk * 4 + 2], a);
          a = fmaf(w.w, h_all[kk * 4 + 3], a);
        }
        po[s] = a + s_blin[glane + 8 * s];
      }
      // max over 24 (fmax is order-insensitive; tree == sequential)
      float mo = fmaxf(fmaxf(po[0], po[1]), po[2]);
      mo = fmaxf(mo, __shfl_xor(mo, 1, 8));
      mo = fmaxf(mo, __shfl_xor(mo, 2, 8));
      mo = fmaxf(mo, __shfl_xor(mo, 4, 8));
#pragma unroll
      for (int s = 0; s < 3; ++s) po[s] = expf(po[s] - mo);
      // XLA shuffle-tree sum: L_j=(x_j+x_{j+16})+x_{j+8}; ((L0+L4)+(L2+L6))+((L1+L5)+(L3+L7))
      const float L = (po[0] + po[2]) + po[1];
      const float v4 = __shfl_down(L, 4, 8);
      const float bb = L + v4;
      const float v2 = __shfl_down(bb, 2, 8);
      const float cc = bb + v2;
      const float v1 = __shfl_down(cc, 1, 8);
      const float sfin = cc + v1;
      const float ssum = __shfl(sfin, 0, 8);
#pragma unroll
      for (int s = 0; s < 3; ++s) po[s] = po[s] / ssum;

      // ===== gather slice (11 normalized p's) — redundant on all lanes =====
      const int count = (sub == 0) ? counter : 11;
      const int add = (sub == 0) ? 12 : 1;
      float q[11];
      if (sub == 0) {
        // p[12..22]: 12..15 -> slot1 lanes 4..7 ; 16..22 -> slot2 lanes 0..6
#pragma unroll
        for (int jj = 0; jj < 4; ++jj) q[jj] = __shfl(po[1], 4 + jj, 8);
#pragma unroll
        for (int jj = 4; jj < 11; ++jj) q[jj] = __shfl(po[2], jj - 4, 8);
      } else {
        // p[0..10]: 0..7 -> slot0 ; 8..10 -> slot1 lanes 0..2
#pragma unroll
        for (int jj = 0; jj < 8; ++jj) q[jj] = __shfl(po[0], jj, 8);
#pragma unroll
        for (int jj = 8; jj < 11; ++jj) q[jj] = __shfl(po[1], jj - 8, 8);
      }

      const float u = rand_u[(size_t)step * BTOT + eb];
      float m2 = q[0];
#pragma unroll
      for (int jj = 1; jj < 11; ++jj)
        if (jj < count) m2 = fmaxf(m2, q[jj]);
#pragma unroll
      for (int jj = 0; jj < 11; ++jj)
        if (jj < count) q[jj] = expf(q[jj] - m2);
      const float qsum = vsumN(q, count);
      float dag[11];
#pragma unroll
      for (int jj = 0; jj < 11; ++jj)
        dag[jj] = (jj < count) ? (q[jj] / qsum) : 0.f;

      float cs[11];
#pragma unroll
      for (int jj = 0; jj < 11; ++jj) cs[jj] = dag[jj];
      ascan11(cs, count);  // jax associative_scan tree

      int idx = -1;
      float pr = 0.f;
#pragma unroll
      for (int jj = 0; jj < 11; ++jj)
        if (jj < count) {
          const bool take = (idx < 0) && (cs[jj] > u);
          idx = take ? jj : idx;
          pr = take ? dag[jj] : pr;
        }
      if (idx < 0) { idx = 0; pr = dag[0]; }  // argmax(all False) = 0

      const int sel = idx + add;
      if (glane == 0) {
        actions[(size_t)eb * NO + step] = (float)sel;
        probs[(size_t)eb * NSTEPS + step] = (float)pr;
      }
      x_idx = sel;
      ++step;
    }
  }
}

}  // namespace

extern "C" void kernel_launch(void* const* d_in, const int* in_sizes, int n_in,
                              void* d_out, int out_size, void* d_ws, size_t ws_size,
                              hipStream_t stream) {
  const float* W_ih = (const float*)d_in[0];
  const float* W_hh = (const float*)d_in[1];
  const float* b_ih = (const float*)d_in[2];
  const float* b_hh = (const float*)d_in[3];
  const float* W_lin = (const float*)d_in[4];
  const float* b_lin = (const float*)d_in[5];
  const float* rand_u = (const float*)d_in[6];
  float* out = (float*)d_out;
  // 131072 elements * 8 lanes / 256 threads = 4096 blocks
  policy_kernel<<<dim3(4096), dim3(256), 0, stream>>>(
      W_ih, W_hh, b_ih, b_hh, W_lin, b_lin, rand_u, out);
}

// Round 14
// 753.802 us; speedup vs baseline: 1.9327x; 1.9327x over previous
//
#include <hip/hip_runtime.h>
#include <math.h>

namespace {

constexpr int BTOT = 131072;
constexpr int HN = 24;
constexpr int NO = 24;
constexpr int NSTEPS = 23;
constexpr int WIH_STRIDE = 100;

// XLA:GPU(ROCm): logistic = 1/(1+exp(-x)) with native ocml expf.
__device__ __forceinline__ float xsig(float x) {
#pragma clang fp contract(off)
  return 1.0f / (1.0f + expf(-x));
}

// XLA:GPU row-reduce, extent 24 (pow2-padded to 32 lanes, init 0):
// shuffle-down tree offsets 16,8,4,2,1.
__device__ __forceinline__ float vsum24(const float* x) {
#pragma clang fp contract(off)
  float L[8];
#pragma unroll
  for (int j = 0; j < 8; ++j) L[j] = (x[j] + x[j + 16]) + x[j + 8];
  float b0 = L[0] + L[4];
  float b1 = L[1] + L[5];
  float b2 = L[2] + L[6];
  float b3 = L[3] + L[7];
  return (b0 + b2) + (b1 + b3);
}

// XLA:GPU row-reduce, extent n<=11 (pow2-padded to 16, init 0).
__device__ __forceinline__ float vsumN(const float* x, int n) {
#pragma clang fp contract(off)
  float t[16];
#pragma unroll
  for (int l = 0; l < 16; ++l) t[l] = (l < n) ? x[l] : 0.f;
  float a[8], b[4], c[2];
#pragma unroll
  for (int l = 0; l < 8; ++l) a[l] = t[l] + t[l + 8];
#pragma unroll
  for (int l = 0; l < 4; ++l) b[l] = a[l] + a[l + 4];
#pragma unroll
  for (int l = 0; l < 2; ++l) c[l] = b[l] + b[l + 2];
  return c[0] + c[1];
}

// jax.lax.associative_scan(add) exact clone for n in [1,11].
__device__ __forceinline__ void ascan11(float* x, int n) {
#pragma clang fp contract(off)
  if (n < 2) return;
  const int m1 = n >> 1;
  float r1[5];
#pragma unroll
  for (int i = 0; i < 5; ++i)
    if (2 * i + 1 < n) r1[i] = x[2 * i] + x[2 * i + 1];
  float r2[2] = {0.f, 0.f};
#pragma unroll
  for (int i = 0; i < 2; ++i)
    if (2 * i + 1 < m1) r2[i] = r1[2 * i] + r1[2 * i + 1];
  const int m2 = m1 >> 1;
  float s2[2];
  s2[0] = r2[0];
  s2[1] = (m2 == 2) ? (r2[0] + r2[1]) : r2[1];
  float s1[5];
  s1[0] = r1[0];
  if (1 < m1) s1[1] = s2[0];
  if (2 < m1) s1[2] = s2[0] + r1[2];
  if (3 < m1) s1[3] = s2[1];
  if (4 < m1) s1[4] = s2[1] + r1[4];
  float o[11];
  o[0] = x[0];
#pragma unroll
  for (int i = 0; i < 5; ++i) {
    if (2 * i + 1 < n) o[2 * i + 1] = s1[i];
    if (2 * i + 2 < n) o[2 * i + 2] = s1[i] + x[2 * i + 2];
  }
#pragma unroll
  for (int i = 0; i < 11; ++i)
    if (i < n) x[i] = o[i];
}

// (256,1): min 1 block/CU -> VGPR budget up to 512/wave. Occupancy is
// grid-limited (2048 waves = 2/SIMD) regardless; registers are free.
// R11 profile: VGPR=108 + ~127MB scratch-spill writes. Goal: 0 spill.
__global__ __launch_bounds__(256, 1) void policy_kernel(
    const float* __restrict__ W_ih, const float* __restrict__ W_hh,
    const float* __restrict__ b_ih, const float* __restrict__ b_hh,
    const float* __restrict__ W_lin, const float* __restrict__ b_lin,
    const float* __restrict__ rand_u, float* __restrict__ out) {
#pragma clang fp contract(off)
  __shared__ __align__(16) float s_wih[23 * WIH_STRIDE];
  for (int t = threadIdx.x; t < 23 * 96; t += 256) {
    const int col = t / 96;
    const int r = t - col * 96;
    s_wih[col * WIH_STRIDE + r] = W_ih[((r & 3) * 24 + (r >> 2)) * NO + col];
  }
  __syncthreads();

  const int e = blockIdx.x * 256 + threadIdx.x;
  float* actions = out;                    // [B][24]
  float* probs = out + (size_t)BTOT * NO;  // [B][23]

  // Preload all 23 uniforms (coalesced; hides per-step load latency).
  float u_all[NSTEPS];
#pragma unroll
  for (int s = 0; s < NSTEPS; ++s) u_all[s] = rand_u[(size_t)s * BTOT + e];

  float h[HN], c[HN];
#pragma unroll
  for (int k = 0; k < HN; ++k) { h[k] = 0.f; c[k] = 0.f; }

  int x_idx = -1;  // -1 => x all zeros (first step)
  int step = 0;
  actions[(size_t)e * NO + 23] = 0.0f;

#pragma unroll 1
  for (int counter = 0; counter < 12; ++counter) {
#pragma unroll 1
    for (int sub = (counter == 0) ? 1 : 0; sub < 2; ++sub) {
      const bool first_step = (counter == 0 && sub == 1);

      // ===== LSTM cell =====
      if (first_step) {
        // h==0, c==0, x==0 exactly: dot chains are exact +0; gates reduce
        // bitwise to ((0+0)+b_ih[j])+b_hh[j].
#pragma unroll
        for (int j = 0; j < HN; ++j) {
          const float gi = ((0.0f + 0.0f) + b_ih[j]) + b_hh[j];
          const float gf = ((0.0f + 0.0f) + b_ih[j + 24]) + b_hh[j + 24];
          const float gg = ((0.0f + 0.0f) + b_ih[j + 48]) + b_hh[j + 48];
          const float go = ((0.0f + 0.0f) + b_ih[j + 72]) + b_hh[j + 72];
          const float t1 = xsig(gf) * c[j];
          const float t2 = xsig(gi) * tanhf(gg);
          const float c2 = t1 + t2;
          c[j] = c2;
          h[j] = xsig(go) * tanhf(c2);  // old h dead (was 0) — in-place ok
        }
      } else {
        const int xcol = (x_idx < 0) ? 0 : x_idx;
        const bool hasx = (x_idx >= 0);
        float hn[HN];
#pragma unroll
        for (int j = 0; j < HN; ++j) {
          const float4 wv =
              *reinterpret_cast<const float4*>(&s_wih[xcol * WIH_STRIDE + j * 4]);
          float ai = 0.f, af = 0.f, ag = 0.f, ao = 0.f;
#pragma unroll
          for (int k = 0; k < HN; ++k) {
            const float hk = h[k];
            ai = fmaf(W_hh[(j)*HN + k], hk, ai);
            af = fmaf(W_hh[(j + 24) * HN + k], hk, af);
            ag = fmaf(W_hh[(j + 48) * HN + k], hk, ag);
            ao = fmaf(W_hh[(j + 72) * HN + k], hk, ao);
          }
          const float gi = (((hasx ? wv.x : 0.f) + ai) + b_ih[j]) + b_hh[j];
          const float gf = (((hasx ? wv.y : 0.f) + af) + b_ih[j + 24]) + b_hh[j + 24];
          const float gg = (((hasx ? wv.z : 0.f) + ag) + b_ih[j + 48]) + b_hh[j + 48];
          const float go = (((hasx ? wv.w : 0.f) + ao) + b_ih[j + 72]) + b_hh[j + 72];
          const float t1 = xsig(gf) * c[j];
          const float t2 = xsig(gi) * tanhf(gg);
          const float c2 = t1 + t2;
          c[j] = c2;
          hn[j] = xsig(go) * tanhf(c2);
        }
#pragma unroll
        for (int j = 0; j < HN; ++j) h[j] = hn[j];
      }

      // ===== counter==1 DAG step: sample is deterministic =====
      // dag = softmax(p[12:13]) = [1.0f] exactly (exp(0)/1 = 1); cs[0]=1.0>u
      // for all u in [0,1) -> idx=0, pr=1.0f, sel=12. Softmax p unused.
      if (sub == 0 && counter == 1) {
        actions[(size_t)e * NO + step] = 12.0f;
        probs[(size_t)e * NSTEPS + step] = 1.0f;
        x_idx = 12;
        ++step;
        continue;
      }

      // ===== p-logits + exp (GPU shuffle-tree sum over 24) =====
      float p[NO];
#pragma unroll
      for (int o = 0; o < NO; ++o) {
        float a = 0.f;
#pragma unroll
        for (int k = 0; k < HN; ++k) a = fmaf(W_lin[o * HN + k], h[k], a);
        p[o] = a + b_lin[o];
      }
      float m = p[0];
#pragma unroll
      for (int o = 1; o < NO; ++o) m = fmaxf(m, p[o]);
#pragma unroll
      for (int o = 0; o < NO; ++o) p[o] = expf(p[o] - m);
      const float ssum = vsum24(p);
      // only the consumed slice is normalized (bitwise-identical values)

      // ===== slice softmax + tree cumsum sample =====
      const int count = (sub == 0) ? counter : 11;
      const int add = (sub == 0) ? 12 : 1;
      float q[11];
#pragma unroll
      for (int jj = 0; jj < 11; ++jj)
        q[jj] = ((sub == 0) ? p[12 + jj] : p[jj]) / ssum;

      const float u = u_all[step];
      float m2 = q[0];
#pragma unroll
      for (int jj = 1; jj < 11; ++jj)
        if (jj < count) m2 = fmaxf(m2, q[jj]);
#pragma unroll
      for (int jj = 0; jj < 11; ++jj)
        if (jj < count) q[jj] = expf(q[jj] - m2);
      const float qsum = vsumN(q, count);
      float dag[11];
#pragma unroll
      for (int jj = 0; jj < 11; ++jj)
        dag[jj] = (jj < count) ? (q[jj] / qsum) : 0.f;

      float cs[11];
#pragma unroll
      for (int jj = 0; jj < 11; ++jj) cs[jj] = dag[jj];
      ascan11(cs, count);  // jax associative_scan tree

      int idx = -1;
      float pr = 0.f;
#pragma unroll
      for (int jj = 0; jj < 11; ++jj)
        if (jj < count) {
          const bool take = (idx < 0) && (cs[jj] > u);
          idx = take ? jj : idx;
          pr = take ? dag[jj] : pr;
        }
      if (idx < 0) { idx = 0; pr = dag[0]; }  // argmax(all False) = 0

      const int sel = idx + add;
      actions[(size_t)e * NO + step] = (float)sel;
      probs[(size_t)e * NSTEPS + step] = (float)pr;
      x_idx = sel;
      ++step;
    }
  }
}

}  // namespace

extern "C" void kernel_launch(void* const* d_in, const int* in_sizes, int n_in,
                              void* d_out, int out_size, void* d_ws, size_t ws_size,
                              hipStream_t stream) {
  const float* W_ih = (const float*)d_in[0];
  const float* W_hh = (const float*)d_in[1];
  const float* b_ih = (const float*)d_in[2];
  const float* b_hh = (const float*)d_in[3];
  const float* W_lin = (const float*)d_in[4];
  const float* b_lin = (const float*)d_in[5];
  const float* rand_u = (const float*)d_in[6];
  float* out = (float*)d_out;
  policy_kernel<<<dim3(BTOT / 256), dim3(256), 0, stream>>>(
      W_ih, W_hh, b_ih, b_hh, W_lin, b_lin, rand_u, out);
}